// Round 2
// baseline (182.680 us; speedup 1.0000x reference)
//
#include <hip/hip_runtime.h>
#include <cstdint>

// Problem constants (from reference): features (B=4, C=256, H=64, W=64) fp32,
// rois (N=2000, 5) fp32, output (N, C, 7, 7) fp32.
constexpr int CCH = 256;
constexpr int HH  = 64;
constexpr int WW  = 64;
constexpr int OHW = 49;          // 7*7 pooled outputs per (n,c)
constexpr float RSCALE = 0.0625f;

// Bit-exact fp32 ops (match numpy/XLA: no FMA contraction on the coordinate
// path — validity test xs<64 is the only discontinuity in the op).
#define FMUL __fmul_rn
#define FADD __fadd_rn
#define FSUB __fsub_rn
#define FDIV __fdiv_rn

// ---------------------------------------------------------------------------
// Kernel 1: transpose features (B, C, H*W) -> (B, H*W, C) so that the gather
// in the main kernel reads channels contiguously (4 cache lines per wave load
// instead of 64).
// ---------------------------------------------------------------------------
__global__ __launch_bounds__(256) void ktranspose(const float* __restrict__ in,
                                                  float* __restrict__ out) {
  __shared__ float tile[32][33];           // +1 pad: conflict-free
  const int b  = blockIdx.z;
  const int s0 = blockIdx.x * 32;          // spatial (h*W+w) tile origin
  const int c0 = blockIdx.y * 32;          // channel tile origin
  const int tx = threadIdx.x;              // 0..31
  const int ty = threadIdx.y;              // 0..7
  const float* inb = in  + (size_t)b * CCH * (HH * WW);
  float*      outb = out + (size_t)b * (HH * WW) * CCH;
#pragma unroll
  for (int i = 0; i < 32; i += 8)
    tile[ty + i][tx] = inb[(size_t)(c0 + ty + i) * (HH * WW) + (s0 + tx)];
  __syncthreads();
#pragma unroll
  for (int i = 0; i < 32; i += 8)
    outb[(size_t)(s0 + ty + i) * CCH + (c0 + tx)] = tile[tx][ty + i];
}

// ---------------------------------------------------------------------------
// Kernel 2: fused RoIAlign (8x8 single-sample bilinear grid) + 2x2 s1 maxpool.
// One block per roi, thread = channel (wave-uniform roi -> zero divergence).
// Rows are streamed with a running horizontal max (only 2 rows live).
// Output staged in LDS (stride 49 = conflict-free) then stored as coalesced
// float4 (direct stores would be 196B-strided scalars -> ~41us of lines).
// TR=true reads the (B,H,W,C) transposed copy in d_ws.
// ---------------------------------------------------------------------------
template <bool TR>
__global__ __launch_bounds__(256) void roi_kernel(const float* __restrict__ feat,
                                                  const float* __restrict__ rois,
                                                  float* __restrict__ out) {
  __shared__ float sout[CCH * OHW];        // 50176 B
  const int n = blockIdx.x;
  const int c = threadIdx.x;               // channel 0..255

  const float rb = rois[n * 5 + 0];
  const float x1 = FMUL(rois[n * 5 + 1], RSCALE);
  const float y1 = FMUL(rois[n * 5 + 2], RSCALE);
  const float x2 = FMUL(rois[n * 5 + 3], RSCALE);
  const float y2 = FMUL(rois[n * 5 + 4], RSCALE);
  const int b = (int)rb;
  const float bh = FDIV(FSUB(y2, y1), 7.0f);
  const float bw = FDIV(FSUB(x2, x1), 7.0f);

  // Per-axis sample data (identical in all lanes; cheap, register-resident).
  int ix0[8], ix1[8], iy0[8], iy1[8];
  float lx[8], ly[8];
  bool xv[8], yv[8];
#pragma unroll
  for (int i = 0; i < 8; ++i) {
    const float xs = FADD(x1, FMUL(bw, (float)i));
    const float ys = FADD(y1, FMUL(bh, (float)i));
    xv[i] = (xs >= 0.0f) && (xs < (float)WW);
    yv[i] = (ys >= 0.0f) && (ys < (float)HH);
    const float xf = floorf(xs);
    const float yf = floorf(ys);
    lx[i] = FSUB(xs, xf);
    ly[i] = FSUB(ys, yf);
    int a = (int)xf;
    a = a < 0 ? 0 : (a > WW - 1 ? WW - 1 : a);
    ix0[i] = a;
    ix1[i] = (a + 1 > WW - 1) ? WW - 1 : a + 1;
    int d = (int)yf;
    d = d < 0 ? 0 : (d > HH - 1 ? HH - 1 : d);
    iy0[i] = d;
    iy1[i] = (d + 1 > HH - 1) ? HH - 1 : d + 1;
  }

  const float* fb;
  if (TR) fb = feat + (size_t)b * (HH * WW * CCH) + c;                 // (B,H,W,C)
  else    fb = feat + ((size_t)b * CCH + c) * (size_t)(HH * WW);       // (B,C,H,W)

  float hp[7];                             // previous row's horizontal max
#pragma unroll
  for (int j = 0; j < 8; ++j) {
    float v[8];
    const float wy1 = ly[j], wy0 = 1.0f - ly[j];
#pragma unroll
    for (int i = 0; i < 8; ++i) {
      if (yv[j] && xv[i]) {                // wave-uniform branch
        float f00, f01, f10, f11;
        if (TR) {
          f00 = fb[(size_t)(iy0[j] * WW + ix0[i]) * CCH];
          f01 = fb[(size_t)(iy0[j] * WW + ix1[i]) * CCH];
          f10 = fb[(size_t)(iy1[j] * WW + ix0[i]) * CCH];
          f11 = fb[(size_t)(iy1[j] * WW + ix1[i]) * CCH];
        } else {
          f00 = fb[iy0[j] * WW + ix0[i]];
          f01 = fb[iy0[j] * WW + ix1[i]];
          f10 = fb[iy1[j] * WW + ix0[i]];
          f11 = fb[iy1[j] * WW + ix1[i]];
        }
        const float wx1 = lx[i], wx0 = 1.0f - lx[i];
        v[i] = wy0 * (wx0 * f00 + wx1 * f01) + wy1 * (wx0 * f10 + wx1 * f11);
      } else {
        v[i] = 0.0f;
      }
    }
    float hc[7];
#pragma unroll
    for (int i = 0; i < 7; ++i) hc[i] = fmaxf(v[i], v[i + 1]);
    if (j > 0) {
      const int oy = j - 1;
#pragma unroll
      for (int i = 0; i < 7; ++i)
        sout[c * OHW + oy * 7 + i] = fmaxf(hp[i], hc[i]);
    }
#pragma unroll
    for (int i = 0; i < 7; ++i) hp[i] = hc[i];
  }

  __syncthreads();
  // Coalesced float4 writeback of this roi's (C,7,7) block: 12544 floats.
  const float4* s4 = (const float4*)sout;
  float4* o4 = (float4*)(out + (size_t)n * (CCH * OHW));
  for (int t = c; t < (CCH * OHW) / 4; t += 256) o4[t] = s4[t];
}

extern "C" void kernel_launch(void* const* d_in, const int* in_sizes, int n_in,
                              void* d_out, int out_size, void* d_ws, size_t ws_size,
                              hipStream_t stream) {
  (void)n_in; (void)out_size;
  const float* feat = (const float*)d_in[0];
  const float* rois = (const float*)d_in[1];
  float* out = (float*)d_out;
  const int N = in_sizes[1] / 5;                       // 2000 rois
  const int B = in_sizes[0] / (CCH * HH * WW);         // 4
  const size_t tneed = (size_t)in_sizes[0] * sizeof(float);

  if (ws_size >= tneed) {
    ktranspose<<<dim3((HH * WW) / 32, CCH / 32, B), dim3(32, 8), 0, stream>>>(
        feat, (float*)d_ws);
    roi_kernel<true><<<dim3(N), dim3(256), 0, stream>>>(
        (const float*)d_ws, rois, out);
  } else {
    // Workspace too small for the transposed copy: slower but correct path.
    roi_kernel<false><<<dim3(N), dim3(256), 0, stream>>>(feat, rois, out);
  }
}